// Round 15
// baseline (1840.654 us; speedup 1.0000x reference)
//
#include <hip/hip_runtime.h>
#include <hip/hip_bf16.h>
#include <math.h>

typedef __bf16 bf16;
typedef __bf16 bf16x8 __attribute__((ext_vector_type(8)));
typedef __bf16 bf16x4 __attribute__((ext_vector_type(4)));
typedef float  f32x4  __attribute__((ext_vector_type(4)));

#define DEV __device__ __forceinline__

DEV void lds_load16(const void* g, void* l) {
  __builtin_amdgcn_global_load_lds(
      (__attribute__((address_space(1))) unsigned int*)g,
      (__attribute__((address_space(3))) unsigned int*)l, 16, 0, 0);
}

DEV f32x4 mfma16(bf16x8 a, bf16x8 b, f32x4 c) {
  return __builtin_amdgcn_mfma_f32_16x16x32_bf16(a, b, c, 0, 0, 0);
}

// bijective XCD swizzle (m204)
DEV int xcd_swz(int flat, int nwg) {
  int q = nwg >> 3, r = nwg & 7;
  int xcd = flat & 7, idx = flat >> 3;
  return (xcd < r ? xcd * (q + 1) : r * (q + 1) + (xcd - r) * q) + idx;
}

// ------------------------- fp32 [R][C] -> bf16 [C][R], layer dim = blockIdx.z
__global__ __launch_bounds__(256) void transpose_cvt(
    const float* __restrict__ in0, bf16* __restrict__ out0, int R, int C) {
  __shared__ float t[64][65];
  size_t zo = (size_t)blockIdx.z * R * C;
  const float* in = in0 + zo;
  bf16* out = out0 + zo;
  int c0 = blockIdx.x * 64, r0 = blockIdx.y * 64;
  int tr = threadIdx.x >> 4, tc4 = (threadIdx.x & 15) * 4;
#pragma unroll
  for (int i = 0; i < 4; i++) {
    float4 v = *(const float4*)(in + (size_t)(r0 + tr + i * 16) * C + c0 + tc4);
    t[tr + i * 16][tc4 + 0] = v.x;
    t[tr + i * 16][tc4 + 1] = v.y;
    t[tr + i * 16][tc4 + 2] = v.z;
    t[tr + i * 16][tc4 + 3] = v.w;
  }
  __syncthreads();
  int oc = threadIdx.x >> 2, j = threadIdx.x & 3;
  bf16x8 o0, o1;
#pragma unroll
  for (int i = 0; i < 8; i++) o0[i] = (bf16)t[j * 16 + i][oc];
#pragma unroll
  for (int i = 0; i < 8; i++) o1[i] = (bf16)t[j * 16 + 8 + i][oc];
  bf16* op = out + (size_t)(c0 + oc) * R + r0 + j * 16;
  *(bf16x8*)op = o0;
  *(bf16x8*)(op + 8) = o1;
}

// ----------------------------------------------------- layernorm (+x->h copy)
__global__ __launch_bounds__(256) void ln_fwd(
    const float* __restrict__ x, const float* __restrict__ gw,
    const float* __restrict__ bw, bf16* __restrict__ y,
    float* __restrict__ hout) {
  int row = blockIdx.x, tid = threadIdx.x;
  const float4 v = ((const float4*)(x + (size_t)row * 1024))[tid];
  if (hout) ((float4*)(hout + (size_t)row * 1024))[tid] = v;
  float s  = v.x + v.y + v.z + v.w;
  float s2 = v.x * v.x + v.y * v.y + v.z * v.z + v.w * v.w;
#pragma unroll
  for (int o = 1; o < 64; o <<= 1) {
    s  += __shfl_xor(s, o);
    s2 += __shfl_xor(s2, o);
  }
  __shared__ float ps[4], ps2[4];
  int wv = tid >> 6;
  if ((tid & 63) == 0) { ps[wv] = s; ps2[wv] = s2; }
  __syncthreads();
  s  = ps[0] + ps[1] + ps[2] + ps[3];
  s2 = ps2[0] + ps2[1] + ps2[2] + ps2[3];
  float mu  = s * (1.f / 1024.f);
  float var = s2 * (1.f / 1024.f) - mu * mu;
  float rs  = rsqrtf(var + 1e-5f);
  float4 gv = ((const float4*)gw)[tid];
  float4 bv = ((const float4*)bw)[tid];
  bf16x4 o4;
  o4[0] = (bf16)((v.x - mu) * rs * gv.x + bv.x);
  o4[1] = (bf16)((v.y - mu) * rs * gv.y + bv.y);
  o4[2] = (bf16)((v.z - mu) * rs * gv.z + bv.z);
  o4[3] = (bf16)((v.w - mu) * rs * gv.w + bv.w);
  *(bf16x4*)(y + (size_t)row * 1024 + tid * 4) = o4;
}

// ------------------------- split-K reduce (bf16 partials) + bias + resid + LN
__global__ __launch_bounds__(256) void reduce_ln(
    const bf16* __restrict__ parts, int nparts, const float* __restrict__ bias,
    float* __restrict__ h, const float* __restrict__ gw,
    const float* __restrict__ bw, bf16* __restrict__ y) {
  const int row = blockIdx.x, tid = threadIdx.x;
  const size_t MN = (size_t)gridDim.x * 1024;
  const size_t eoff = (size_t)row * 1024 + tid * 4;
  float sx = 0.f, sy = 0.f, sz = 0.f, sw = 0.f;
  for (int p = 0; p < nparts; p++) {
    bf16x4 v = *(const bf16x4*)(parts + (size_t)p * MN + eoff);
    sx += (float)v[0]; sy += (float)v[1]; sz += (float)v[2]; sw += (float)v[3];
  }
  const size_t rb = (size_t)row * 256;
  const float4 bb = ((const float4*)bias)[tid];
  float4 r = ((float4*)h)[rb + tid];
  r.x += sx + bb.x; r.y += sy + bb.y; r.z += sz + bb.z; r.w += sw + bb.w;
  ((float4*)h)[rb + tid] = r;
  if (gw == nullptr) return;
  float sm  = r.x + r.y + r.z + r.w;
  float sm2 = r.x * r.x + r.y * r.y + r.z * r.z + r.w * r.w;
#pragma unroll
  for (int o = 1; o < 64; o <<= 1) {
    sm  += __shfl_xor(sm, o);
    sm2 += __shfl_xor(sm2, o);
  }
  __shared__ float ps[4], ps2[4];
  int wv = tid >> 6;
  if ((tid & 63) == 0) { ps[wv] = sm; ps2[wv] = sm2; }
  __syncthreads();
  sm  = ps[0] + ps[1] + ps[2] + ps[3];
  sm2 = ps2[0] + ps2[1] + ps2[2] + ps2[3];
  float mu  = sm * (1.f / 1024.f);
  float var = sm2 * (1.f / 1024.f) - mu * mu;
  float rs  = rsqrtf(var + 1e-5f);
  float4 gv = ((const float4*)gw)[tid];
  float4 bv = ((const float4*)bw)[tid];
  bf16x4 o4;
  o4[0] = (bf16)((r.x - mu) * rs * gv.x + bv.x);
  o4[1] = (bf16)((r.y - mu) * rs * gv.y + bv.y);
  o4[2] = (bf16)((r.z - mu) * rs * gv.z + bv.z);
  o4[3] = (bf16)((r.w - mu) * rs * gv.w + bv.w);
  *(bf16x4*)(y + (size_t)row * 1024 + tid * 4) = o4;
}

// --------------------------------------------------------------- GEMM 8-phase
// (round-3 skeleton) + T1 XCD swizzle. BM=128, BN=256, BK=64, 8 waves (2Mx4N).
// Used for QKV (control).
// EPI: 0 = bf16 out (+bias)
template <int EPI>
__global__ __launch_bounds__(512, 2) void gemm8p(
    const bf16* __restrict__ A, const bf16* __restrict__ Bt,
    const float* __restrict__ bias, bf16* __restrict__ outb,
    int M, int N, int K, int kcount) {
  __shared__ __align__(16) char lds[3 * 49152];  // per buf: A 16K, B 32K
  const int tid = threadIdx.x, wv = tid >> 6, lane = tid & 63;
  const int g = lane >> 4, lr = lane & 15;
  const int wr = wv >> 2, wc = wv & 3;
  const int nwg = gridDim.x * gridDim.y;
  const int wgid = xcd_swz(blockIdx.y * gridDim.x + blockIdx.x, nwg);
  const int bn = wgid % gridDim.x, bm = wgid / gridDim.x;
  const int kbegin = blockIdx.z * kcount;
  const bf16* Ab = A + (size_t)bm * 128 * K + kbegin;
  const bf16* Bb = Bt + (size_t)bn * 256 * K + kbegin;
  const int nt = kcount >> 6;

  f32x4 acc[4][4] = {};

  auto stageA = [&](int t) {
    char* dst = lds + (t % 3) * 49152;
    int k0 = t * 64;
#pragma unroll
    for (int c = 0; c < 2; c++) {
      int off = c * 8192 + tid * 16;
      int row = off >> 7, cb = off & 127;
      int cbs = cb ^ ((row & 7) << 4);
      lds_load16((const char*)(Ab + (size_t)row * K + k0) + cbs, dst + off);
    }
  };
  auto stageB = [&](int t, int half) {
    char* dst = lds + (t % 3) * 49152 + 16384 + half * 16384;
    int k0 = t * 64;
#pragma unroll
    for (int c = 0; c < 2; c++) {
      int off = c * 8192 + tid * 16;
      int row = (off >> 7) + half * 128, cb = off & 127;
      int cbs = cb ^ ((row & 7) << 4);
      lds_load16((const char*)(Bb + (size_t)row * K + k0) + cbs, dst + off);
    }
  };
  auto ldA = [&](int t, int m, int kk) -> bf16x8 {
    const char* base = lds + (t % 3) * 49152;
    int row = wr * 64 + m * 16 + lr;
    int col = (kk * 64 + g * 16) ^ ((row & 7) << 4);
    return *(const bf16x8*)(base + row * 128 + col);
  };
  auto ldB = [&](int t, int n, int kk) -> bf16x8 {
    const char* base = lds + (t % 3) * 49152 + 16384;
    int row = wc * 64 + n * 16 + lr;
    int col = (kk * 64 + g * 16) ^ ((row & 7) << 4);
    return *(const bf16x8*)(base + row * 128 + col);
  };

  stageA(0); stageB(0, 0); stageB(0, 1);
  if (nt > 1) {
    stageA(1); stageB(1, 0); stageB(1, 1);
    asm volatile("s_waitcnt vmcnt(6)" ::: "memory");
  } else {
    asm volatile("s_waitcnt vmcnt(0)" ::: "memory");
  }
  __builtin_amdgcn_s_barrier();

  bf16x8 a[4][2], b[4][2];
  for (int t = 0; t < nt; ++t) {
#pragma unroll
    for (int m = 0; m < 4; m++)
#pragma unroll
      for (int kk = 0; kk < 2; kk++) a[m][kk] = ldA(t, m, kk);
#pragma unroll
    for (int n = 0; n < 2; n++)
#pragma unroll
      for (int kk = 0; kk < 2; kk++) b[n][kk] = ldB(t, n, kk);
    if (t + 2 < nt) { stageA(t + 2); stageB(t + 2, 0); }
    __builtin_amdgcn_s_barrier();
    asm volatile("s_waitcnt lgkmcnt(0)" ::: "memory");
    __builtin_amdgcn_sched_barrier(0);
    __builtin_amdgcn_s_setprio(1);
#pragma unroll
    for (int m = 0; m < 4; m++)
#pragma unroll
      for (int n = 0; n < 2; n++)
#pragma unroll
        for (int kk = 0; kk < 2; kk++)
          acc[m][n] = mfma16(a[m][kk], b[n][kk], acc[m][n]);
    __builtin_amdgcn_s_setprio(0);
    __builtin_amdgcn_s_barrier();
#pragma unroll
    for (int n = 2; n < 4; n++)
#pragma unroll
      for (int kk = 0; kk < 2; kk++) b[n][kk] = ldB(t, n, kk);
    if (t + 2 < nt) {
      stageB(t + 2, 1);
      asm volatile("s_waitcnt vmcnt(6)" ::: "memory");
    } else if (t + 1 < nt) {
      asm volatile("s_waitcnt vmcnt(0)" ::: "memory");
    }
    __builtin_amdgcn_s_barrier();
    asm volatile("s_waitcnt lgkmcnt(0)" ::: "memory");
    __builtin_amdgcn_sched_barrier(0);
    __builtin_amdgcn_s_setprio(1);
#pragma unroll
    for (int m = 0; m < 4; m++)
#pragma unroll
      for (int n = 2; n < 4; n++)
#pragma unroll
        for (int kk = 0; kk < 2; kk++)
          acc[m][n] = mfma16(a[m][kk], b[n][kk], acc[m][n]);
    __builtin_amdgcn_s_setprio(0);
    __builtin_amdgcn_s_barrier();
  }

#pragma unroll
  for (int m = 0; m < 4; m++) {
#pragma unroll
    for (int n = 0; n < 4; n++) {
      int col = bn * 256 + wc * 64 + n * 16 + lr;
      float bv = bias[col];
#pragma unroll
      for (int r = 0; r < 4; r++) {
        int row = bm * 128 + wr * 64 + m * 16 + g * 4 + r;
        outb[(size_t)row * N + col] = (bf16)(acc[m][n][r] + bv);
      }
    }
  }
}

// ---------------------------------------- GEMM 4-wave, 128x128 tile, BK=32
// (round-6 gemm32 skeleton, halved block). 4 waves (2Mx2N), per-wave 64x64.
// 3-slot LDS 48KB -> 3 blocks/CU capacity; at >=512 wg grids, 2 independent
// blocks/CU overlap each other's barrier stalls. Structural vmcnt(4).
// Swizzle for 64B rows: byte ^= ((row>>1)&3)<<4.
// EPI: 2 = bf16 out gelu(+bias), 3 = bf16 partial (split-K over z)
template <int EPI>
__global__ __launch_bounds__(256, 3) void gemm4w(
    const bf16* __restrict__ A, const bf16* __restrict__ Bt,
    const float* __restrict__ bias, bf16* __restrict__ outb,
    int M, int N, int K, int kcount) {
  constexpr int SLOT = (128 + 128) * 32 * 2;    // 16384 B: A 8K + B 8K
  __shared__ __align__(16) char lds[3 * SLOT];  // 48 KB
  const int tid = threadIdx.x, wv = tid >> 6, lane = tid & 63;
  const int g = lane >> 4, lr = lane & 15;
  const int wr = wv >> 1, wc = wv & 1;
  const int nwg = gridDim.x * gridDim.y;
  const int wgid = xcd_swz(blockIdx.y * gridDim.x + blockIdx.x, nwg);
  const int bn = wgid % gridDim.x, bm = wgid / gridDim.x;
  const int kbegin = blockIdx.z * kcount;
  const bf16* Ab = A + (size_t)bm * 128 * K + kbegin;
  const bf16* Bb = Bt + (size_t)bn * 128 * K + kbegin;
  const int nt = kcount >> 5;
  f32x4 acc[4][4] = {};

  auto stage = [&](int t) {  // 4 x 16B loads per thread (A:2, B:2)
    char* dst = lds + (t % 3) * SLOT;
#pragma unroll
    for (int c = 0; c < 2; c++) {
      int off = c * 4096 + tid * 16;
      int row = off >> 6, cb = off & 63;
      int cbs = cb ^ (((row >> 1) & 3) << 4);
      lds_load16((const char*)(Ab + (size_t)row * K + t * 32) + cbs, dst + off);
    }
#pragma unroll
    for (int c = 0; c < 2; c++) {
      int off = c * 4096 + tid * 16;
      int row = off >> 6, cb = off & 63;
      int cbs = cb ^ (((row >> 1) & 3) << 4);
      lds_load16((const char*)(Bb + (size_t)row * K + t * 32) + cbs,
                 dst + 8192 + off);
    }
  };
  auto ldA = [&](int t, int m) -> bf16x8 {
    const char* base = lds + (t % 3) * SLOT;
    int row = wr * 64 + m * 16 + lr;
    int col = (g * 16) ^ (((row >> 1) & 3) << 4);
    return *(const bf16x8*)(base + row * 64 + col);
  };
  auto ldB = [&](int t, int n) -> bf16x8 {
    const char* base = lds + (t % 3) * SLOT + 8192;
    int row = wc * 64 + n * 16 + lr;
    int col = (g * 16) ^ (((row >> 1) & 3) << 4);
    return *(const bf16x8*)(base + row * 64 + col);
  };

  stage(0);
  stage(1);

  for (int t = 0; t < nt; ++t) {
    if (t + 1 < nt)
      asm volatile("s_waitcnt vmcnt(4)" ::: "memory");
    else
      asm volatile("s_waitcnt vmcnt(0)" ::: "memory");
    __builtin_amdgcn_s_barrier();
    bf16x8 a[4], b[4];
#pragma unroll
    for (int m = 0; m < 4; m++) a[m] = ldA(t, m);
#pragma unroll
    for (int n = 0; n < 4; n++) b[n] = ldB(t, n);
    if (t + 2 < nt) stage(t + 2);
    asm volatile("s_waitcnt lgkmcnt(0)" ::: "memory");
    __builtin_amdgcn_sched_barrier(0);
    __builtin_amdgcn_s_setprio(1);
#pragma unroll
    for (int m = 0; m < 4; m++)
#pragma unroll
      for (int n = 0; n < 4; n++)
        acc[m][n] = mfma16(a[m], b[n], acc[m][n]);
    __builtin_amdgcn_s_setprio(0);
  }

  bf16* ob = (EPI == 3) ? outb + (size_t)blockIdx.z * M * N : outb;
#pragma unroll
  for (int m = 0; m < 4; m++) {
#pragma unroll
    for (int n = 0; n < 4; n++) {
      int col = bn * 128 + wc * 64 + n * 16 + lr;
      float bv = (EPI == 3) ? 0.f : bias[col];
#pragma unroll
      for (int r = 0; r < 4; r++) {
        int row = bm * 128 + wr * 64 + m * 16 + g * 4 + r;
        size_t idx = (size_t)row * N + col;
        float v = acc[m][n][r] + bv;
        if (EPI == 2) {
          ob[idx] = (bf16)(0.5f * v * (1.f + erff(v * 0.70710678118f)));
        } else {
          ob[idx] = (bf16)v;
        }
      }
    }
  }
}

// --------------------------------------------------------------- attention
// QBLK=64, 4 waves x 16 q-rows, XCD-swizzled; K/V dbuf, 1 barrier/tile;
// exp2-domain softmax + defer-max.
__global__ __launch_bounds__(256) void attn_fwd(
    const bf16* __restrict__ qkv, bf16* __restrict__ outp) {
  __shared__ __align__(16) bf16 Kls[2][128 * 64];
  __shared__ __align__(16) bf16 Vt[2][64 * 128];
  __shared__ __align__(16) bf16 Pls[4 * 16 * 128];
  const int tid = threadIdx.x, wv = tid >> 6, lane = tid & 63;
  const int g = lane >> 4, lr = lane & 15;
  const int wgid = xcd_swz(blockIdx.y * gridDim.x + blockIdx.x,
                           gridDim.x * gridDim.y);
  const int bh = wgid / gridDim.x, bb = bh >> 4, hh = bh & 15;
  const int q0 = (wgid % gridDim.x) * 64;
  const bf16* base = qkv + (size_t)bb * 1024 * 3072;
  const int qc = hh * 192, kc = qc + 64, vc = qc + 128;

  auto kstage = [&](int t, int buf) {
#pragma unroll
    for (int c = 0; c < 4; c++) {
      int off = wv * 4096 + c * 1024 + lane * 16;
      int s = off >> 7, cb = off & 127;
      int cbs = cb ^ ((s & 7) << 4);
      lds_load16(
          (const char*)(base + (size_t)(t * 128 + s) * 3072 + kc) + cbs,
          (char*)Kls[buf] + off);
    }
  };

  bf16x8 aq[2];
  {
    int row = q0 + wv * 16 + lr;
#pragma unroll
    for (int kk = 0; kk < 2; kk++) {
      bf16x8 v = *(const bf16x8*)(base + (size_t)row * 3072 + qc + kk * 32 + g * 8);
#pragma unroll
      for (int j = 0; j < 8; j++) v[j] = (bf16)((float)v[j] * 0.1803368801f);
      aq[kk] = v;
    }
  }

  f32x4 o[4] = {};
  float rm[4], rl[4];
#pragma unroll
  for (int r = 0; r < 4; r++) { rm[r] = -1e30f; rl[r] = 0.f; }

  kstage(0, 0);
#pragma unroll
  for (int it = 0; it < 2; it++) {
    int idx = it * 256 + tid;
    int s = (idx >> 3) * 2, c0i = (idx & 7) * 8;
    bf16x8 v0 = *(const bf16x8*)(base + (size_t)s * 3072 + vc + c0i);
    bf16x8 v1 = *(const bf16x8*)(base + (size_t)(s + 1) * 3072 + vc + c0i);
#pragma unroll
    for (int j = 0; j < 8; j++) {
      int c = c0i + j;
      unsigned int pk = (unsigned int)__builtin_bit_cast(unsigned short, v0[j]) |
                        ((unsigned int)__builtin_bit_cast(unsigned short, v1[j]) << 16);
      *(unsigned int*)((char*)Vt[0] + c * 256 + ((s * 2) ^ ((c & 7) << 4))) = pk;
    }
  }

  for (int ti = 0; ti < 8; ++ti) {
    const int cur = ti & 1, nxt = cur ^ 1;
    __syncthreads();
    f32x4 sa[8] = {};
#pragma unroll
    for (int kk = 0; kk < 2; kk++) {
#pragma unroll
      for (int n = 0; n < 8; n++) {
        int srow = n * 16 + lr;
        int cbyte = (kk * 32 + g * 8) * 2;
        bf16x8 kb = *(const bf16x8*)((char*)Kls[cur] + srow * 128 +
                                     (cbyte ^ ((srow & 7) << 4)));
        sa[n] = mfma16(aq[kk], kb, sa[n]);
      }
    }
    bf16x8 vreg[2][2];
    if (ti + 1 < 8) {
      kstage(ti + 1, nxt);
#pragma unroll
      for (int it = 0; it < 2; it++) {
        int idx = it * 256 + tid;
        int s = (idx >> 3) * 2, c0i = (idx & 7) * 8;
        vreg[it][0] = *(const bf16x8*)(
            base + (size_t)((ti + 1) * 128 + s) * 3072 + vc + c0i);
        vreg[it][1] = *(const bf16x8*)(
            base + (size_t)((ti + 1) * 128 + s + 1) * 3072 + vc + c0i);
      }
    }
    float al[4];
#pragma unroll
    for (int r = 0; r < 4; r++) {
      float tm = -1e30f;
#pragma unroll
      for (int n = 0; n < 8; n++) tm = fmaxf(tm, sa[n][r]);
      tm = fmaxf(tm, __shfl_xor(tm, 1));
      tm = fmaxf(tm, __shfl_xor(tm, 2));
      tm = fmaxf(tm, __shfl_xor(tm, 4));
      tm = fmaxf(tm, __shfl_xor(tm, 8));
      if (tm - rm[r] <= 11.0f) {
        al[r] = 1.0f;
      } else {
        al[r] = exp2f(rm[r] - tm);
        rm[r] = tm;
      }
    }
    float psum[4] = {0.f, 0.f, 0.f, 0.f};
#pragma unroll
    for (int n = 0; n < 8; n++) {
#pragma unroll
      for (int r = 0; r < 4; r++) {
        float p = exp2f(sa[n][r] - rm[r]);
        psum[r] += p;
        int rw = g * 4 + r;
        int sb = (n * 16 + lr) * 2;
        *(bf16*)((char*)Pls + wv * 4096 + rw * 256 + (sb ^ ((rw & 7) << 4))) =
            (bf16)p;
      }
    }
#pragma unroll
    for (int r = 0; r < 4; r++) {
      psum[r] += __shfl_xor(psum[r], 1);
      psum[r] += __shfl_xor(psum[r], 2);
      psum[r] += __shfl_xor(psum[r], 4);
      psum[r] += __shfl_xor(psum[r], 8);
      rl[r] = rl[r] * al[r] + psum[r];
      if (al[r] != 1.0f) {
#pragma unroll
        for (int n = 0; n < 4; n++) o[n][r] *= al[r];
      }
    }
    asm volatile("s_waitcnt lgkmcnt(0)" ::: "memory");
    __builtin_amdgcn_sched_barrier(0);
#pragma unroll
    for (int sc = 0; sc < 4; sc++) {
      int sb = (sc * 32 + g * 8) * 2;
      bf16x8 pa = *(const bf16x8*)((char*)Pls + wv * 4096 + lr * 256 +
                                   (sb ^ ((lr & 7) << 4)));
#pragma unroll
      for (int n = 0; n < 4; n++) {
        int c = n * 16 + lr;
        bf16x8 vb = *(const bf16x8*)((char*)Vt[cur] + c * 256 +
                                     (sb ^ ((c & 7) << 4)));
        o[n] = mfma16(pa, vb, o[n]);
      }
    }
    if (ti + 1 < 8) {
#pragma unroll
      for (int it = 0; it < 2; it++) {
        int idx = it * 256 + tid;
        int s = (idx >> 3) * 2, c0i = (idx & 7) * 8;
#pragma unroll
        for (int j = 0; j < 8; j++) {
          int c = c0i + j;
          unsigned int pk =
              (unsigned int)__builtin_bit_cast(unsigned short, vreg[it][0][j]) |
              ((unsigned int)__builtin_bit_cast(unsigned short, vreg[it][1][j])
               << 16);
          *(unsigned int*)((char*)Vt[nxt] + c * 256 + ((s * 2) ^ ((c & 7) << 4))) =
              pk;
        }
      }
    }
  }
#pragma unroll
  for (int n = 0; n < 4; n++)
#pragma unroll
    for (int r = 0; r < 4; r++) {
      int row = q0 + wv * 16 + g * 4 + r;
      int col = hh * 64 + n * 16 + lr;
      outp[(size_t)(bb * 1024 + row) * 1024 + col] = (bf16)(o[n][r] / rl[r]);
    }
}

// ------------------------------------------------------------------- host
extern "C" void kernel_launch(void* const* d_in, const int* in_sizes, int n_in,
                              void* d_out, int out_size, void* d_ws,
                              size_t ws_size, hipStream_t stream) {
  const float* x      = (const float*)d_in[0];
  const float* qkv_w  = (const float*)d_in[1];
  const float* qkv_b  = (const float*)d_in[2];
  const float* proj_w = (const float*)d_in[3];
  const float* proj_b = (const float*)d_in[4];
  const float* ln1_g  = (const float*)d_in[5];
  const float* ln1_b  = (const float*)d_in[6];
  const float* ln2_g  = (const float*)d_in[7];
  const float* ln2_b  = (const float*)d_in[8];
  const float* fc_w   = (const float*)d_in[9];
  const float* fc_b   = (const float*)d_in[10];
  const float* fc2_w  = (const float*)d_in[11];
  const float* fc2_b  = (const float*)d_in[12];
  float* h = (float*)d_out;

  char* ws = (char*)d_ws;
  size_t off = 0;
  auto alloc = [&](size_t bytes) -> char* {
    char* p = ws + off;
    off = (off + bytes + 255) & ~(size_t)255;
    return p;
  };
  bf16* wq_t    = (bf16*)alloc((size_t)12 * 3072 * 1024 * 2);
  bf16* wp_t    = (bf16*)alloc((size_t)12 * 1024 * 1024 * 2);
  bf16* wf_t    = (bf16*)alloc((size_t)12 * 4096 * 1024 * 2);
  bf16* w2_t    = (bf16*)alloc((size_t)12 * 1024 * 4096 * 2);
  bf16* lnbuf   = (bf16*)alloc((size_t)2048 * 1024 * 2);
  bf16* qkvbuf  = (bf16*)alloc((size_t)2048 * 3072 * 2);
  bf16* attnbuf = (bf16*)alloc((size_t)2048 * 1024 * 2);
  bf16* fcbuf   = (bf16*)alloc((size_t)2048 * 4096 * 2);
  bf16* partbuf = (bf16*)alloc((size_t)4 * 2048 * 1024 * 2);

  transpose_cvt<<<dim3(48, 16, 12), 256, 0, stream>>>(qkv_w, wq_t, 1024, 3072);
  transpose_cvt<<<dim3(16, 16, 12), 256, 0, stream>>>(proj_w, wp_t, 1024, 1024);
  transpose_cvt<<<dim3(64, 16, 12), 256, 0, stream>>>(fc_w, wf_t, 1024, 4096);
  transpose_cvt<<<dim3(16, 64, 12), 256, 0, stream>>>(fc2_w, w2_t, 4096, 1024);

  ln_fwd<<<2048, 256, 0, stream>>>(x, ln1_g, ln1_b, lnbuf, h);

  for (int l = 0; l < 12; l++) {
    const bf16* wq = wq_t + (size_t)l * 3072 * 1024;
    const bf16* wp = wp_t + (size_t)l * 1024 * 1024;
    const bf16* wf = wf_t + (size_t)l * 4096 * 1024;
    const bf16* w2 = w2_t + (size_t)l * 1024 * 4096;

    gemm8p<0><<<dim3(12, 16, 1), 512, 0, stream>>>(
        lnbuf, wq, qkv_b + (size_t)l * 3072, qkvbuf, 2048, 3072, 1024, 1024);
    attn_fwd<<<dim3(16, 32), 256, 0, stream>>>(qkvbuf, attnbuf);
    gemm4w<3><<<dim3(8, 16, 4), 256, 0, stream>>>(
        attnbuf, wp, nullptr, partbuf, 2048, 1024, 1024, 256);
    reduce_ln<<<2048, 256, 0, stream>>>(partbuf, 4, proj_b + (size_t)l * 1024,
                                        h, ln2_g + (size_t)l * 1024,
                                        ln2_b + (size_t)l * 1024, lnbuf);
    gemm4w<2><<<dim3(32, 16, 1), 256, 0, stream>>>(
        lnbuf, wf, fc_b + (size_t)l * 4096, fcbuf, 2048, 4096, 1024, 1024);
    gemm4w<3><<<dim3(8, 16, 4), 256, 0, stream>>>(
        fcbuf, w2, nullptr, partbuf, 2048, 1024, 4096, 1024);
    if (l < 11) {
      reduce_ln<<<2048, 256, 0, stream>>>(
          partbuf, 4, fc2_b + (size_t)l * 1024, h,
          ln1_g + (size_t)(l + 1) * 1024, ln1_b + (size_t)(l + 1) * 1024,
          lnbuf);
    } else {
      reduce_ln<<<2048, 256, 0, stream>>>(partbuf, 4,
                                          fc2_b + (size_t)l * 1024, h, nullptr,
                                          nullptr, nullptr);
    }
  }
}

// Round 16
// 1761.985 us; speedup vs baseline: 1.0446x; 1.0446x over previous
//
#include <hip/hip_runtime.h>
#include <hip/hip_bf16.h>
#include <math.h>

typedef __bf16 bf16;
typedef __bf16 bf16x8 __attribute__((ext_vector_type(8)));
typedef __bf16 bf16x4 __attribute__((ext_vector_type(4)));
typedef float  f32x4  __attribute__((ext_vector_type(4)));

#define DEV __device__ __forceinline__

DEV void lds_load16(const void* g, void* l) {
  __builtin_amdgcn_global_load_lds(
      (__attribute__((address_space(1))) unsigned int*)g,
      (__attribute__((address_space(3))) unsigned int*)l, 16, 0, 0);
}

DEV f32x4 mfma16(bf16x8 a, bf16x8 b, f32x4 c) {
  return __builtin_amdgcn_mfma_f32_16x16x32_bf16(a, b, c, 0, 0, 0);
}

// bijective XCD swizzle (m204)
DEV int xcd_swz(int flat, int nwg) {
  int q = nwg >> 3, r = nwg & 7;
  int xcd = flat & 7, idx = flat >> 3;
  return (xcd < r ? xcd * (q + 1) : r * (q + 1) + (xcd - r) * q) + idx;
}

// ------------------------- fp32 [R][C] -> bf16 [C][R], layer dim = blockIdx.z
__global__ __launch_bounds__(256) void transpose_cvt(
    const float* __restrict__ in0, bf16* __restrict__ out0, int R, int C) {
  __shared__ float t[64][65];
  size_t zo = (size_t)blockIdx.z * R * C;
  const float* in = in0 + zo;
  bf16* out = out0 + zo;
  int c0 = blockIdx.x * 64, r0 = blockIdx.y * 64;
  int tr = threadIdx.x >> 4, tc4 = (threadIdx.x & 15) * 4;
#pragma unroll
  for (int i = 0; i < 4; i++) {
    float4 v = *(const float4*)(in + (size_t)(r0 + tr + i * 16) * C + c0 + tc4);
    t[tr + i * 16][tc4 + 0] = v.x;
    t[tr + i * 16][tc4 + 1] = v.y;
    t[tr + i * 16][tc4 + 2] = v.z;
    t[tr + i * 16][tc4 + 3] = v.w;
  }
  __syncthreads();
  int oc = threadIdx.x >> 2, j = threadIdx.x & 3;
  bf16x8 o0, o1;
#pragma unroll
  for (int i = 0; i < 8; i++) o0[i] = (bf16)t[j * 16 + i][oc];
#pragma unroll
  for (int i = 0; i < 8; i++) o1[i] = (bf16)t[j * 16 + 8 + i][oc];
  bf16* op = out + (size_t)(c0 + oc) * R + r0 + j * 16;
  *(bf16x8*)op = o0;
  *(bf16x8*)(op + 8) = o1;
}

// ----------------------------------------------------- layernorm (+x->h copy)
__global__ __launch_bounds__(256) void ln_fwd(
    const float* __restrict__ x, const float* __restrict__ gw,
    const float* __restrict__ bw, bf16* __restrict__ y,
    float* __restrict__ hout) {
  int row = blockIdx.x, tid = threadIdx.x;
  const float4 v = ((const float4*)(x + (size_t)row * 1024))[tid];
  if (hout) ((float4*)(hout + (size_t)row * 1024))[tid] = v;
  float s  = v.x + v.y + v.z + v.w;
  float s2 = v.x * v.x + v.y * v.y + v.z * v.z + v.w * v.w;
#pragma unroll
  for (int o = 1; o < 64; o <<= 1) {
    s  += __shfl_xor(s, o);
    s2 += __shfl_xor(s2, o);
  }
  __shared__ float ps[4], ps2[4];
  int wv = tid >> 6;
  if ((tid & 63) == 0) { ps[wv] = s; ps2[wv] = s2; }
  __syncthreads();
  s  = ps[0] + ps[1] + ps[2] + ps[3];
  s2 = ps2[0] + ps2[1] + ps2[2] + ps2[3];
  float mu  = s * (1.f / 1024.f);
  float var = s2 * (1.f / 1024.f) - mu * mu;
  float rs  = rsqrtf(var + 1e-5f);
  float4 gv = ((const float4*)gw)[tid];
  float4 bv = ((const float4*)bw)[tid];
  bf16x4 o4;
  o4[0] = (bf16)((v.x - mu) * rs * gv.x + bv.x);
  o4[1] = (bf16)((v.y - mu) * rs * gv.y + bv.y);
  o4[2] = (bf16)((v.z - mu) * rs * gv.z + bv.z);
  o4[3] = (bf16)((v.w - mu) * rs * gv.w + bv.w);
  *(bf16x4*)(y + (size_t)row * 1024 + tid * 4) = o4;
}

// ------------------------- split-K reduce (bf16 partials) + bias + resid + LN
__global__ __launch_bounds__(256) void reduce_ln(
    const bf16* __restrict__ parts, int nparts, const float* __restrict__ bias,
    float* __restrict__ h, const float* __restrict__ gw,
    const float* __restrict__ bw, bf16* __restrict__ y) {
  const int row = blockIdx.x, tid = threadIdx.x;
  const size_t MN = (size_t)gridDim.x * 1024;
  const size_t eoff = (size_t)row * 1024 + tid * 4;
  float sx = 0.f, sy = 0.f, sz = 0.f, sw = 0.f;
  for (int p = 0; p < nparts; p++) {
    bf16x4 v = *(const bf16x4*)(parts + (size_t)p * MN + eoff);
    sx += (float)v[0]; sy += (float)v[1]; sz += (float)v[2]; sw += (float)v[3];
  }
  const size_t rb = (size_t)row * 256;
  const float4 bb = ((const float4*)bias)[tid];
  float4 r = ((float4*)h)[rb + tid];
  r.x += sx + bb.x; r.y += sy + bb.y; r.z += sz + bb.z; r.w += sw + bb.w;
  ((float4*)h)[rb + tid] = r;
  if (gw == nullptr) return;
  float sm  = r.x + r.y + r.z + r.w;
  float sm2 = r.x * r.x + r.y * r.y + r.z * r.z + r.w * r.w;
#pragma unroll
  for (int o = 1; o < 64; o <<= 1) {
    sm  += __shfl_xor(sm, o);
    sm2 += __shfl_xor(sm2, o);
  }
  __shared__ float ps[4], ps2[4];
  int wv = tid >> 6;
  if ((tid & 63) == 0) { ps[wv] = sm; ps2[wv] = sm2; }
  __syncthreads();
  sm  = ps[0] + ps[1] + ps[2] + ps[3];
  sm2 = ps2[0] + ps2[1] + ps2[2] + ps2[3];
  float mu  = sm * (1.f / 1024.f);
  float var = sm2 * (1.f / 1024.f) - mu * mu;
  float rs  = rsqrtf(var + 1e-5f);
  float4 gv = ((const float4*)gw)[tid];
  float4 bv = ((const float4*)bw)[tid];
  bf16x4 o4;
  o4[0] = (bf16)((r.x - mu) * rs * gv.x + bv.x);
  o4[1] = (bf16)((r.y - mu) * rs * gv.y + bv.y);
  o4[2] = (bf16)((r.z - mu) * rs * gv.z + bv.z);
  o4[3] = (bf16)((r.w - mu) * rs * gv.w + bv.w);
  *(bf16x4*)(y + (size_t)row * 1024 + tid * 4) = o4;
}

// --------------------------------------------------------------- GEMM 8-phase
// (round-3 skeleton) + T1 XCD swizzle. BM=128, BN=256, BK=64, 8 waves (2Mx4N).
// EPI: 0 = bf16 out (+bias), 2 = bf16 out gelu(+bias),
//      3 = bf16 partial (split-K over blockIdx.z, no bias)
template <int EPI>
__global__ __launch_bounds__(512, 2) void gemm8p(
    const bf16* __restrict__ A, const bf16* __restrict__ Bt,
    const float* __restrict__ bias, bf16* __restrict__ outb,
    int M, int N, int K, int kcount) {
  __shared__ __align__(16) char lds[3 * 49152];  // per buf: A 16K, B 32K
  const int tid = threadIdx.x, wv = tid >> 6, lane = tid & 63;
  const int g = lane >> 4, lr = lane & 15;
  const int wr = wv >> 2, wc = wv & 3;
  const int nwg = gridDim.x * gridDim.y;
  const int wgid = xcd_swz(blockIdx.y * gridDim.x + blockIdx.x, nwg);
  const int bn = wgid % gridDim.x, bm = wgid / gridDim.x;
  const int kbegin = blockIdx.z * kcount;
  const bf16* Ab = A + (size_t)bm * 128 * K + kbegin;
  const bf16* Bb = Bt + (size_t)bn * 256 * K + kbegin;
  const int nt = kcount >> 6;

  f32x4 acc[4][4] = {};

  auto stageA = [&](int t) {
    char* dst = lds + (t % 3) * 49152;
    int k0 = t * 64;
#pragma unroll
    for (int c = 0; c < 2; c++) {
      int off = c * 8192 + tid * 16;
      int row = off >> 7, cb = off & 127;
      int cbs = cb ^ ((row & 7) << 4);
      lds_load16((const char*)(Ab + (size_t)row * K + k0) + cbs, dst + off);
    }
  };
  auto stageB = [&](int t, int half) {
    char* dst = lds + (t % 3) * 49152 + 16384 + half * 16384;
    int k0 = t * 64;
#pragma unroll
    for (int c = 0; c < 2; c++) {
      int off = c * 8192 + tid * 16;
      int row = (off >> 7) + half * 128, cb = off & 127;
      int cbs = cb ^ ((row & 7) << 4);
      lds_load16((const char*)(Bb + (size_t)row * K + k0) + cbs, dst + off);
    }
  };
  auto ldA = [&](int t, int m, int kk) -> bf16x8 {
    const char* base = lds + (t % 3) * 49152;
    int row = wr * 64 + m * 16 + lr;
    int col = (kk * 64 + g * 16) ^ ((row & 7) << 4);
    return *(const bf16x8*)(base + row * 128 + col);
  };
  auto ldB = [&](int t, int n, int kk) -> bf16x8 {
    const char* base = lds + (t % 3) * 49152 + 16384;
    int row = wc * 64 + n * 16 + lr;
    int col = (kk * 64 + g * 16) ^ ((row & 7) << 4);
    return *(const bf16x8*)(base + row * 128 + col);
  };

  stageA(0); stageB(0, 0); stageB(0, 1);
  if (nt > 1) {
    stageA(1); stageB(1, 0); stageB(1, 1);
    asm volatile("s_waitcnt vmcnt(6)" ::: "memory");
  } else {
    asm volatile("s_waitcnt vmcnt(0)" ::: "memory");
  }
  __builtin_amdgcn_s_barrier();

  bf16x8 a[4][2], b[4][2];
  for (int t = 0; t < nt; ++t) {
#pragma unroll
    for (int m = 0; m < 4; m++)
#pragma unroll
      for (int kk = 0; kk < 2; kk++) a[m][kk] = ldA(t, m, kk);
#pragma unroll
    for (int n = 0; n < 2; n++)
#pragma unroll
      for (int kk = 0; kk < 2; kk++) b[n][kk] = ldB(t, n, kk);
    if (t + 2 < nt) { stageA(t + 2); stageB(t + 2, 0); }
    __builtin_amdgcn_s_barrier();
    asm volatile("s_waitcnt lgkmcnt(0)" ::: "memory");
    __builtin_amdgcn_sched_barrier(0);
    __builtin_amdgcn_s_setprio(1);
#pragma unroll
    for (int m = 0; m < 4; m++)
#pragma unroll
      for (int n = 0; n < 2; n++)
#pragma unroll
        for (int kk = 0; kk < 2; kk++)
          acc[m][n] = mfma16(a[m][kk], b[n][kk], acc[m][n]);
    __builtin_amdgcn_s_setprio(0);
    __builtin_amdgcn_s_barrier();
#pragma unroll
    for (int n = 2; n < 4; n++)
#pragma unroll
      for (int kk = 0; kk < 2; kk++) b[n][kk] = ldB(t, n, kk);
    if (t + 2 < nt) {
      stageB(t + 2, 1);
      asm volatile("s_waitcnt vmcnt(6)" ::: "memory");
    } else if (t + 1 < nt) {
      asm volatile("s_waitcnt vmcnt(0)" ::: "memory");
    }
    __builtin_amdgcn_s_barrier();
    asm volatile("s_waitcnt lgkmcnt(0)" ::: "memory");
    __builtin_amdgcn_sched_barrier(0);
    __builtin_amdgcn_s_setprio(1);
#pragma unroll
    for (int m = 0; m < 4; m++)
#pragma unroll
      for (int n = 2; n < 4; n++)
#pragma unroll
        for (int kk = 0; kk < 2; kk++)
          acc[m][n] = mfma16(a[m][kk], b[n][kk], acc[m][n]);
    __builtin_amdgcn_s_setprio(0);
    __builtin_amdgcn_s_barrier();
  }

  bf16* ob = (EPI == 3) ? outb + (size_t)blockIdx.z * M * N : outb;
#pragma unroll
  for (int m = 0; m < 4; m++) {
#pragma unroll
    for (int n = 0; n < 4; n++) {
      int col = bn * 256 + wc * 64 + n * 16 + lr;
      float bv = (EPI == 3) ? 0.f : bias[col];
#pragma unroll
      for (int r = 0; r < 4; r++) {
        int row = bm * 128 + wr * 64 + m * 16 + g * 4 + r;
        size_t idx = (size_t)row * N + col;
        float v = acc[m][n][r] + bv;
        if (EPI == 2) {
          ob[idx] = (bf16)(0.5f * v * (1.f + erff(v * 0.70710678118f)));
        } else {
          ob[idx] = (bf16)v;
        }
      }
    }
  }
}

// --------------------------------------------------------------- attention
// QBLK=64, 4 waves x 16 q-rows, XCD-swizzled; K/V dbuf, 1 barrier/tile;
// exp2-domain softmax + defer-max.
__global__ __launch_bounds__(256) void attn_fwd(
    const bf16* __restrict__ qkv, bf16* __restrict__ outp) {
  __shared__ __align__(16) bf16 Kls[2][128 * 64];
  __shared__ __align__(16) bf16 Vt[2][64 * 128];
  __shared__ __align__(16) bf16 Pls[4 * 16 * 128];
  const int tid = threadIdx.x, wv = tid >> 6, lane = tid & 63;
  const int g = lane >> 4, lr = lane & 15;
  const int wgid = xcd_swz(blockIdx.y * gridDim.x + blockIdx.x,
                           gridDim.x * gridDim.y);
  const int bh = wgid / gridDim.x, bb = bh >> 4, hh = bh & 15;
  const int q0 = (wgid % gridDim.x) * 64;
  const bf16* base = qkv + (size_t)bb * 1024 * 3072;
  const int qc = hh * 192, kc = qc + 64, vc = qc + 128;

  auto kstage = [&](int t, int buf) {
#pragma unroll
    for (int c = 0; c < 4; c++) {
      int off = wv * 4096 + c * 1024 + lane * 16;
      int s = off >> 7, cb = off & 127;
      int cbs = cb ^ ((s & 7) << 4);
      lds_load16(
          (const char*)(base + (size_t)(t * 128 + s) * 3072 + kc) + cbs,
          (char*)Kls[buf] + off);
    }
  };

  bf16x8 aq[2];
  {
    int row = q0 + wv * 16 + lr;
#pragma unroll
    for (int kk = 0; kk < 2; kk++) {
      bf16x8 v = *(const bf16x8*)(base + (size_t)row * 3072 + qc + kk * 32 + g * 8);
#pragma unroll
      for (int j = 0; j < 8; j++) v[j] = (bf16)((float)v[j] * 0.1803368801f);
      aq[kk] = v;
    }
  }

  f32x4 o[4] = {};
  float rm[4], rl[4];
#pragma unroll
  for (int r = 0; r < 4; r++) { rm[r] = -1e30f; rl[r] = 0.f; }

  kstage(0, 0);
#pragma unroll
  for (int it = 0; it < 2; it++) {
    int idx = it * 256 + tid;
    int s = (idx >> 3) * 2, c0i = (idx & 7) * 8;
    bf16x8 v0 = *(const bf16x8*)(base + (size_t)s * 3072 + vc + c0i);
    bf16x8 v1 = *(const bf16x8*)(base + (size_t)(s + 1) * 3072 + vc + c0i);
#pragma unroll
    for (int j = 0; j < 8; j++) {
      int c = c0i + j;
      unsigned int pk = (unsigned int)__builtin_bit_cast(unsigned short, v0[j]) |
                        ((unsigned int)__builtin_bit_cast(unsigned short, v1[j]) << 16);
      *(unsigned int*)((char*)Vt[0] + c * 256 + ((s * 2) ^ ((c & 7) << 4))) = pk;
    }
  }

  for (int ti = 0; ti < 8; ++ti) {
    const int cur = ti & 1, nxt = cur ^ 1;
    __syncthreads();
    f32x4 sa[8] = {};
#pragma unroll
    for (int kk = 0; kk < 2; kk++) {
#pragma unroll
      for (int n = 0; n < 8; n++) {
        int srow = n * 16 + lr;
        int cbyte = (kk * 32 + g * 8) * 2;
        bf16x8 kb = *(const bf16x8*)((char*)Kls[cur] + srow * 128 +
                                     (cbyte ^ ((srow & 7) << 4)));
        sa[n] = mfma16(aq[kk], kb, sa[n]);
      }
    }
    bf16x8 vreg[2][2];
    if (ti + 1 < 8) {
      kstage(ti + 1, nxt);
#pragma unroll
      for (int it = 0; it < 2; it++) {
        int idx = it * 256 + tid;
        int s = (idx >> 3) * 2, c0i = (idx & 7) * 8;
        vreg[it][0] = *(const bf16x8*)(
            base + (size_t)((ti + 1) * 128 + s) * 3072 + vc + c0i);
        vreg[it][1] = *(const bf16x8*)(
            base + (size_t)((ti + 1) * 128 + s + 1) * 3072 + vc + c0i);
      }
    }
    float al[4];
#pragma unroll
    for (int r = 0; r < 4; r++) {
      float tm = -1e30f;
#pragma unroll
      for (int n = 0; n < 8; n++) tm = fmaxf(tm, sa[n][r]);
      tm = fmaxf(tm, __shfl_xor(tm, 1));
      tm = fmaxf(tm, __shfl_xor(tm, 2));
      tm = fmaxf(tm, __shfl_xor(tm, 4));
      tm = fmaxf(tm, __shfl_xor(tm, 8));
      if (tm - rm[r] <= 11.0f) {
        al[r] = 1.0f;
      } else {
        al[r] = exp2f(rm[r] - tm);
        rm[r] = tm;
      }
    }
    float psum[4] = {0.f, 0.f, 0.f, 0.f};
#pragma unroll
    for (int n = 0; n < 8; n++) {
#pragma unroll
      for (int r = 0; r < 4; r++) {
        float p = exp2f(sa[n][r] - rm[r]);
        psum[r] += p;
        int rw = g * 4 + r;
        int sb = (n * 16 + lr) * 2;
        *(bf16*)((char*)Pls + wv * 4096 + rw * 256 + (sb ^ ((rw & 7) << 4))) =
            (bf16)p;
      }
    }
#pragma unroll
    for (int r = 0; r < 4; r++) {
      psum[r] += __shfl_xor(psum[r], 1);
      psum[r] += __shfl_xor(psum[r], 2);
      psum[r] += __shfl_xor(psum[r], 4);
      psum[r] += __shfl_xor(psum[r], 8);
      rl[r] = rl[r] * al[r] + psum[r];
      if (al[r] != 1.0f) {
#pragma unroll
        for (int n = 0; n < 4; n++) o[n][r] *= al[r];
      }
    }
    asm volatile("s_waitcnt lgkmcnt(0)" ::: "memory");
    __builtin_amdgcn_sched_barrier(0);
#pragma unroll
    for (int sc = 0; sc < 4; sc++) {
      int sb = (sc * 32 + g * 8) * 2;
      bf16x8 pa = *(const bf16x8*)((char*)Pls + wv * 4096 + lr * 256 +
                                   (sb ^ ((lr & 7) << 4)));
#pragma unroll
      for (int n = 0; n < 4; n++) {
        int c = n * 16 + lr;
        bf16x8 vb = *(const bf16x8*)((char*)Vt[cur] + c * 256 +
                                     (sb ^ ((c & 7) << 4)));
        o[n] = mfma16(pa, vb, o[n]);
      }
    }
    if (ti + 1 < 8) {
#pragma unroll
      for (int it = 0; it < 2; it++) {
        int idx = it * 256 + tid;
        int s = (idx >> 3) * 2, c0i = (idx & 7) * 8;
#pragma unroll
        for (int j = 0; j < 8; j++) {
          int c = c0i + j;
          unsigned int pk =
              (unsigned int)__builtin_bit_cast(unsigned short, vreg[it][0][j]) |
              ((unsigned int)__builtin_bit_cast(unsigned short, vreg[it][1][j])
               << 16);
          *(unsigned int*)((char*)Vt[nxt] + c * 256 + ((s * 2) ^ ((c & 7) << 4))) =
              pk;
        }
      }
    }
  }
#pragma unroll
  for (int n = 0; n < 4; n++)
#pragma unroll
    for (int r = 0; r < 4; r++) {
      int row = q0 + wv * 16 + g * 4 + r;
      int col = hh * 64 + n * 16 + lr;
      outp[(size_t)(bb * 1024 + row) * 1024 + col] = (bf16)(o[n][r] / rl[r]);
    }
}

// ------------------------------------------------------------------- host
extern "C" void kernel_launch(void* const* d_in, const int* in_sizes, int n_in,
                              void* d_out, int out_size, void* d_ws,
                              size_t ws_size, hipStream_t stream) {
  const float* x      = (const float*)d_in[0];
  const float* qkv_w  = (const float*)d_in[1];
  const float* qkv_b  = (const float*)d_in[2];
  const float* proj_w = (const float*)d_in[3];
  const float* proj_b = (const float*)d_in[4];
  const float* ln1_g  = (const float*)d_in[5];
  const float* ln1_b  = (const float*)d_in[6];
  const float* ln2_g  = (const float*)d_in[7];
  const float* ln2_b  = (const float*)d_in[8];
  const float* fc_w   = (const float*)d_in[9];
  const float* fc_b   = (const float*)d_in[10];
  const float* fc2_w  = (const float*)d_in[11];
  const float* fc2_b  = (const float*)d_in[12];
  float* h = (float*)d_out;

  char* ws = (char*)d_ws;
  size_t off = 0;
  auto alloc = [&](size_t bytes) -> char* {
    char* p = ws + off;
    off = (off + bytes + 255) & ~(size_t)255;
    return p;
  };
  bf16* wq_t    = (bf16*)alloc((size_t)12 * 3072 * 1024 * 2);
  bf16* wp_t    = (bf16*)alloc((size_t)12 * 1024 * 1024 * 2);
  bf16* wf_t    = (bf16*)alloc((size_t)12 * 4096 * 1024 * 2);
  bf16* w2_t    = (bf16*)alloc((size_t)12 * 1024 * 4096 * 2);
  bf16* lnbuf   = (bf16*)alloc((size_t)2048 * 1024 * 2);
  bf16* qkvbuf  = (bf16*)alloc((size_t)2048 * 3072 * 2);
  bf16* attnbuf = (bf16*)alloc((size_t)2048 * 1024 * 2);
  bf16* fcbuf   = (bf16*)alloc((size_t)2048 * 4096 * 2);
  bf16* partbuf = (bf16*)alloc((size_t)4 * 2048 * 1024 * 2);

  transpose_cvt<<<dim3(48, 16, 12), 256, 0, stream>>>(qkv_w, wq_t, 1024, 3072);
  transpose_cvt<<<dim3(16, 16, 12), 256, 0, stream>>>(proj_w, wp_t, 1024, 1024);
  transpose_cvt<<<dim3(64, 16, 12), 256, 0, stream>>>(fc_w, wf_t, 1024, 4096);
  transpose_cvt<<<dim3(16, 64, 12), 256, 0, stream>>>(fc2_w, w2_t, 4096, 1024);

  ln_fwd<<<2048, 256, 0, stream>>>(x, ln1_g, ln1_b, lnbuf, h);

  for (int l = 0; l < 12; l++) {
    const bf16* wq = wq_t + (size_t)l * 3072 * 1024;
    const bf16* wp = wp_t + (size_t)l * 1024 * 1024;
    const bf16* wf = wf_t + (size_t)l * 4096 * 1024;
    const bf16* w2 = w2_t + (size_t)l * 1024 * 4096;

    gemm8p<0><<<dim3(12, 16, 1), 512, 0, stream>>>(
        lnbuf, wq, qkv_b + (size_t)l * 3072, qkvbuf, 2048, 3072, 1024, 1024);
    attn_fwd<<<dim3(16, 32), 256, 0, stream>>>(qkvbuf, attnbuf);
    gemm8p<3><<<dim3(4, 16, 4), 512, 0, stream>>>(
        attnbuf, wp, nullptr, partbuf, 2048, 1024, 1024, 256);
    reduce_ln<<<2048, 256, 0, stream>>>(partbuf, 4, proj_b + (size_t)l * 1024,
                                        h, ln2_g + (size_t)l * 1024,
                                        ln2_b + (size_t)l * 1024, lnbuf);
    gemm8p<2><<<dim3(16, 16, 1), 512, 0, stream>>>(
        lnbuf, wf, fc_b + (size_t)l * 4096, fcbuf, 2048, 4096, 1024, 1024);
    gemm8p<3><<<dim3(4, 16, 4), 512, 0, stream>>>(
        fcbuf, w2, nullptr, partbuf, 2048, 1024, 4096, 1024);
    if (l < 11) {
      reduce_ln<<<2048, 256, 0, stream>>>(
          partbuf, 4, fc2_b + (size_t)l * 1024, h,
          ln1_g + (size_t)(l + 1) * 1024, ln1_b + (size_t)(l + 1) * 1024,
          lnbuf);
    } else {
      reduce_ln<<<2048, 256, 0, stream>>>(partbuf, 4,
                                          fc2_b + (size_t)l * 1024, h, nullptr,
                                          nullptr, nullptr);
    }
  }
}